// Round 8
// baseline (810.171 us; speedup 1.0000x reference)
//
#include <hip/hip_runtime.h>
#include <stdint.h>

// Problem constants: B=8, Cin=Cout=256, H=W=64, H2=W2=128, P=4 points.
#define NB   8
#define CH   256
#define HW0  4096    // 64*64
#define HW2  16384   // 128*128

typedef __attribute__((ext_vector_type(8))) short short8;
typedef __attribute__((ext_vector_type(8))) unsigned short u16x8;
typedef __attribute__((ext_vector_type(4))) unsigned short u16x4;
typedef __attribute__((ext_vector_type(4))) float floatx4;

__device__ inline unsigned short f2bf(float f) {
    union { float f; uint32_t u; } v; v.f = f;
    return (unsigned short)((v.u + 0x7FFFu + ((v.u >> 16) & 1u)) >> 16);
}
__device__ inline float bf2f(unsigned short h) {
    union { uint32_t u; float f; } v; v.u = ((uint32_t)h) << 16;
    return v.f;
}

// ---------------------------------------------------------------------------
// ktrans: [B][256][M] f32  ->  [B][M][256] bf16   (transpose + convert)
// Used only for high_feat (low transpose fused into k2).
// ---------------------------------------------------------------------------
__global__ __launch_bounds__(256) void ktrans(const float* __restrict__ src,
        unsigned short* __restrict__ dst, int M) {
    const int b = blockIdx.z, k0 = blockIdx.y * 32, m0 = blockIdx.x * 128;
    const int tid = threadIdx.x;
    __shared__ unsigned short tile[32][132];
    const float* s = src + ((size_t)b * CH + k0) * M + m0;
    for (int c = tid; c < 1024; c += 256) {
        int kk = c >> 5, mm = (c & 31) * 4;
        float4 v = *(const float4*)(s + (size_t)kk * M + mm);
        u16x4 o = { f2bf(v.x), f2bf(v.y), f2bf(v.z), f2bf(v.w) };
        *(u16x4*)&tile[kk][mm] = o;
    }
    __syncthreads();
    unsigned short* d = dst + ((size_t)b * M + m0) * CH + k0;
    for (int c = tid; c < 512; c += 256) {
        int mm = c >> 2, kc = (c & 3) * 8;
        u16x8 v;
        #pragma unroll
        for (int i = 0; i < 8; ++i) v[i] = tile[kc + i][mm];
        *(u16x8*)(d + (size_t)mm * CH + kc) = v;
    }
}

// ---------------------------------------------------------------------------
// kwconv: pack weights to bf16.  A1[512][256]: rows 0-255 = W1a, 256-511 = Wf.
// A2[256][256] = W1b.
// ---------------------------------------------------------------------------
__global__ __launch_bounds__(256) void kwconv(const float* __restrict__ W1,
        const float* __restrict__ Wf, unsigned short* __restrict__ A1,
        unsigned short* __restrict__ A2) {
    int i = blockIdx.x * 256 + threadIdx.x;
    if (i < 512 * 256) {
        int n = i >> 8, k = i & 255;
        float v = (n < 256) ? W1[n * 512 + k] : Wf[(size_t)(n - 256) * 256 + k];
        A1[i] = f2bf(v);
    }
    if (i < 256 * 256) {
        int n = i >> 8, k = i & 255;
        A2[i] = f2bf(W1[n * 512 + 256 + k]);
    }
}

// ---------------------------------------------------------------------------
// kwpack: W2 [8][256][3][3] f32 -> W3p [9 taps][16 o (8 padded)][256 ci] bf16
// Launched AFTER k1 (reuses the then-dead highT buffer).
// ---------------------------------------------------------------------------
__global__ __launch_bounds__(256) void kwpack(const float* __restrict__ W2v,
        unsigned short* __restrict__ W3p) {
    int i = blockIdx.x * 256 + threadIdx.x;   // 9*16*256 = 36864
    if (i >= 9 * 16 * 256) return;
    int ci = i & 255, o = (i >> 8) & 15, t = i >> 12;
    float v = (o < 8) ? W2v[((size_t)o * 256 + ci) * 9 + t] : 0.0f;
    W3p[i] = f2bf(v);
}

// ---------------------------------------------------------------------------
// K1: dual MFMA GEMM:  D[n,m] = A1[n,:] . highT[m,:]   (k-contig both sides)
//   n<256 -> T[b][n][m]  ; n>=256 -> procT[b][m][n-256] + bf (LDS transpose)
// Flat grid 1024: b = bid&7 (XCD affinity: highT[b] = 2MB fits one XCD L2).
// ---------------------------------------------------------------------------
__global__ __launch_bounds__(256) void k1_mfma(
    const unsigned short* __restrict__ highT,  // [B][4096][256]
    const unsigned short* __restrict__ A1,     // [512][256]
    const float* __restrict__ bfv,
    float* __restrict__ T, float* __restrict__ procT)
{
    const int bid = blockIdx.x;
    const int b  = bid & 7;
    const int q  = bid >> 3;            // 0..127
    const int m0 = (q & 31) * 128;      // over 4096
    const int n0 = (q >> 5) * 128;      // over 512
    const int tid = threadIdx.x;
    __shared__ __attribute__((aligned(16))) unsigned short smem[2 * 128 * 40];
    unsigned short* As = smem;
    unsigned short* Xs = smem + 128 * 40;
    const int lane = tid & 63, wid = tid >> 6;
    const int wn = (wid >> 1) * 64, wm = (wid & 1) * 64;
    const int l15 = lane & 15, quad = lane >> 4;

    floatx4 acc[4][4];
    #pragma unroll
    for (int i = 0; i < 4; ++i)
        #pragma unroll
        for (int j = 0; j < 4; ++j)
            acc[i][j] = (floatx4){0.f, 0.f, 0.f, 0.f};

    const unsigned short* Xg = highT + ((size_t)b * HW0 + m0) * CH;

    for (int k0 = 0; k0 < 256; k0 += 32) {
        for (int c = tid; c < 512; c += 256) {
            int row = c >> 2, kc = (c & 3) * 8;
            *(u16x8*)&As[row * 40 + kc] =
                *(const u16x8*)(A1 + (size_t)(n0 + row) * CH + k0 + kc);
            *(u16x8*)&Xs[row * 40 + kc] =
                *(const u16x8*)(Xg + (size_t)row * CH + k0 + kc);
        }
        __syncthreads();
        short8 af[4], bfr[4];
        #pragma unroll
        for (int i = 0; i < 4; ++i)
            af[i] = *(const short8*)&As[(wn + i * 16 + l15) * 40 + quad * 8];
        #pragma unroll
        for (int j = 0; j < 4; ++j)
            bfr[j] = *(const short8*)&Xs[(wm + j * 16 + l15) * 40 + quad * 8];
        #pragma unroll
        for (int i = 0; i < 4; ++i)
            #pragma unroll
            for (int j = 0; j < 4; ++j)
                acc[i][j] = __builtin_amdgcn_mfma_f32_16x16x32_bf16(
                    af[i], bfr[j], acc[i][j], 0, 0, 0);
        __syncthreads();
    }

    if (n0 < 256) {
        #pragma unroll
        for (int i = 0; i < 4; ++i) {
            int nb = n0 + wn + i * 16 + quad * 4;
            #pragma unroll
            for (int r = 0; r < 4; ++r) {
                int n = nb + r;
                #pragma unroll
                for (int j = 0; j < 4; ++j) {
                    int m = m0 + wm + j * 16 + l15;
                    T[((size_t)b * CH + n) * HW0 + m] = acc[i][j][r];
                }
            }
        }
    } else {
        // LDS transpose: 4 passes over 32-pixel m-quarters.
        float* tf = (float*)smem;
        const int nc = n0 - 256;
        #pragma unroll
        for (int mq = 0; mq < 4; ++mq) {
            __syncthreads();
            if ((wid & 1) == (mq >> 1)) {
                #pragma unroll
                for (int jj = 0; jj < 2; ++jj) {
                    int j = (mq & 1) * 2 + jj;
                    int ml = j * 16 + l15 - (mq & 1) * 32;   // 0..31
                    #pragma unroll
                    for (int i = 0; i < 4; ++i) {
                        int nl = wn + i * 16 + quad * 4;
                        #pragma unroll
                        for (int r = 0; r < 4; ++r)
                            tf[ml * 132 + nl + r] = acc[i][j][r] + bfv[nc + nl + r];
                    }
                }
            }
            __syncthreads();
            int mm = tid >> 3;            // 0..31
            int c8 = tid & 7;
            float* dst = procT + ((size_t)b * HW0 + m0 + mq * 32 + mm) * CH + nc;
            #pragma unroll
            for (int k = 0; k < 4; ++k) {
                int col = c8 * 4 + k * 32;
                *(float4*)(dst + col) = *(const float4*)&tf[mm * 132 + col];
            }
        }
    }
}

// ---------------------------------------------------------------------------
// K2: MFMA GEMM + fused upsample epilogue + FUSED low-transpose:
//   val[n, y, x] = relu( A2[n,:].low[:, y, x] + up2x(T)[n,y,x] + b1[n] )
// Conflict-free 16B LDS staging writes + register double-buffer prefetch.
// Flat grid 2048: b = bid&7 (XCD affinity).
// ---------------------------------------------------------------------------
__global__ __launch_bounds__(256) void k2_mfma(
    const float* __restrict__ low,             // [B][256][128][128] f32
    const unsigned short* __restrict__ A2,     // [256][256]
    const float* __restrict__ b1, const float* __restrict__ T,
    unsigned short* __restrict__ off_featT)
{
    const int bid = blockIdx.x;
    const int b  = bid & 7;
    const int q  = bid >> 3;            // 0..255
    const int y  = q >> 1;              // 0..127
    const int n0 = (q & 1) * 128;
    const int tid = threadIdx.x;
    __shared__ unsigned short smem[2 * 128 * 40];
    unsigned short* As = smem;
    unsigned short* Xs = smem + 128 * 40;
    const int lane = tid & 63, wid = tid >> 6;
    const int wn = (wid >> 1) * 64, wm = (wid & 1) * 64;
    const int l15 = lane & 15, quad = lane >> 4;

    const int rowA = lane + (wid & 1) * 64;
    const int slA  = wid >> 1;                 // slots slA and slA+2
    const float* Lg = low + ((size_t)b * CH + wid * 8) * HW2
                      + (size_t)y * 128 + lane;

    floatx4 acc[4][4];
    #pragma unroll
    for (int i = 0; i < 4; ++i)
        #pragma unroll
        for (int j = 0; j < 4; ++j)
            acc[i][j] = (floatx4){0.f, 0.f, 0.f, 0.f};

    u16x8 aR[2];
    float xR[2][8];

    // prologue: load k0 = 0 into registers
    #pragma unroll
    for (int i = 0; i < 2; ++i)
        aR[i] = *(const u16x8*)(A2 + (size_t)(n0 + rowA) * CH + (slA + i * 2) * 8);
    #pragma unroll
    for (int i = 0; i < 2; ++i)
        #pragma unroll
        for (int c = 0; c < 8; ++c)
            xR[i][c] = Lg[(size_t)c * HW2 + i * 64];

    for (int k0 = 0; k0 < 256; k0 += 32) {
        __syncthreads();        // previous tile's frag reads done
        #pragma unroll
        for (int i = 0; i < 2; ++i)
            *(u16x8*)&As[rowA * 40 + (slA + i * 2) * 8] = aR[i];
        #pragma unroll
        for (int i = 0; i < 2; ++i) {
            u16x8 o = { f2bf(xR[i][0]), f2bf(xR[i][1]), f2bf(xR[i][2]),
                        f2bf(xR[i][3]), f2bf(xR[i][4]), f2bf(xR[i][5]),
                        f2bf(xR[i][6]), f2bf(xR[i][7]) };
            *(u16x8*)&Xs[(lane + i * 64) * 40 + wid * 8] = o;
        }
        __syncthreads();
        if (k0 + 32 < 256) {    // prefetch next k-step (overlaps MFMA below)
            #pragma unroll
            for (int i = 0; i < 2; ++i)
                aR[i] = *(const u16x8*)(A2 + (size_t)(n0 + rowA) * CH
                                        + k0 + 32 + (slA + i * 2) * 8);
            #pragma unroll
            for (int i = 0; i < 2; ++i)
                #pragma unroll
                for (int c = 0; c < 8; ++c)
                    xR[i][c] = Lg[(size_t)(k0 + 32 + c) * HW2 + i * 64];
        }
        short8 af[4], bfr[4];
        #pragma unroll
        for (int i = 0; i < 4; ++i)
            af[i] = *(const short8*)&As[(wn + i * 16 + l15) * 40 + quad * 8];
        #pragma unroll
        for (int j = 0; j < 4; ++j)
            bfr[j] = *(const short8*)&Xs[(wm + j * 16 + l15) * 40 + quad * 8];
        #pragma unroll
        for (int i = 0; i < 4; ++i)
            #pragma unroll
            for (int j = 0; j < 4; ++j)
                acc[i][j] = __builtin_amdgcn_mfma_f32_16x16x32_bf16(
                    af[i], bfr[j], acc[i][j], 0, 0, 0);
    }

    // epilogue: upsample taps. y uniform per block.
    int hk = y >> 1;
    int yA, yB; float wyA, wyB;
    if (y & 1) { yA = hk; yB = min(hk + 1, 63); wyA = 0.75f; wyB = 0.25f; }
    else       { yB = hk; yA = max(hk - 1, 0);  wyA = 0.25f; wyB = 0.75f; }

    int xA[4], xB[4]; float wxA[4], wxB[4];
    #pragma unroll
    for (int j = 0; j < 4; ++j) {
        int x = wm + j * 16 + l15;
        int xk = x >> 1;
        if (x & 1) { xA[j] = xk; xB[j] = min(xk + 1, 63); wxA[j] = 0.75f; wxB[j] = 0.25f; }
        else       { xB[j] = xk; xA[j] = max(xk - 1, 0);  wxA[j] = 0.25f; wxB[j] = 0.75f; }
    }

    #pragma unroll
    for (int i = 0; i < 4; ++i) {
        int nb = n0 + wn + i * 16 + quad * 4;
        #pragma unroll
        for (int r = 0; r < 4; ++r) {
            int n = nb + r;
            const float* tb  = T + ((size_t)b * CH + n) * HW0;
            const float* trA = tb + yA * 64;
            const float* trB = tb + yB * 64;
            float bias = b1[n];
            #pragma unroll
            for (int j = 0; j < 4; ++j) {
                float up = wyA * (wxA[j] * trA[xA[j]] + wxB[j] * trA[xB[j]])
                         + wyB * (wxA[j] * trB[xA[j]] + wxB[j] * trB[xB[j]]);
                acc[i][j][r] = fmaxf(acc[i][j][r] + up + bias, 0.0f);
            }
        }
    }

    // LDS transpose: two passes of [64 x][128 n], write k-contiguous bf16.
    unsigned short (*tile)[136] = (unsigned short (*)[136])smem;
    for (int xh = 0; xh < 2; ++xh) {
        __syncthreads();
        if ((wid & 1) == xh) {
            #pragma unroll
            for (int i = 0; i < 4; ++i) {
                int nc = wn + i * 16 + quad * 4;
                #pragma unroll
                for (int j = 0; j < 4; ++j) {
                    int xr = j * 16 + l15;
                    unsigned int lo = (unsigned int)f2bf(acc[i][j][0])
                                    | ((unsigned int)f2bf(acc[i][j][1]) << 16);
                    unsigned int hi = (unsigned int)f2bf(acc[i][j][2])
                                    | ((unsigned int)f2bf(acc[i][j][3]) << 16);
                    *(unsigned int*)&tile[xr][nc]     = lo;
                    *(unsigned int*)&tile[xr][nc + 2] = hi;
                }
            }
        }
        __syncthreads();
        for (int c = tid; c < 1024; c += 256) {
            int xr = c >> 4, nc = (c & 15) * 8;
            u16x8 v = *(u16x8*)&tile[xr][nc];
            *(u16x8*)(off_featT +
                ((size_t)b * HW2 + (size_t)y * 128 + xh * 64 + xr) * CH + n0 + nc) = v;
        }
    }
}

// ---------------------------------------------------------------------------
// K3: offsets = conv3x3(off_featT, W3p) via MFMA, LDS-staged.
// Block = 32 out px (b, y, xq); 3 rows x 34 px x 256 ch staged swizzled;
// 4 waves split K; f32 LDS reduction.  Flat grid 4096: b = bid&7.
// ---------------------------------------------------------------------------
__global__ __launch_bounds__(256) void k3_mfma(
    const unsigned short* __restrict__ offT,   // [B][16384][256] bf16
    const unsigned short* __restrict__ W3p,    // [9][16][256] bf16
    float* __restrict__ offs)
{
    const int bid = blockIdx.x;
    const int b  = bid & 7;
    const int q  = bid >> 3;       // 0..511
    const int y  = q >> 2;         // 0..127
    const int xq = q & 3;          // 32-px quarter
    const int tid = threadIdx.x;
    const int lane = tid & 63, w = tid >> 6;
    const int l15 = lane & 15, quad = lane >> 4;

    __shared__ __attribute__((aligned(16))) unsigned short st[3 * 34 * 256];

    short8 bw[9][2];
    #pragma unroll
    for (int t = 0; t < 9; ++t)
        #pragma unroll
        for (int k0 = 0; k0 < 2; ++k0)
            bw[t][k0] = *(const short8*)(W3p + (size_t)(t * 16 + l15) * CH
                                         + w * 64 + k0 * 32 + quad * 8);

    const unsigned short* src = offT + (size_t)b * HW2 * CH;
    for (int it = tid; it < 3264; it += 256) {     // 3*34*32 16B tasks
        int s   = it & 31;
        int px  = (it >> 5) % 34;
        int row = it / (34 * 32);
        int gy = y - 1 + row;
        int gx = xq * 32 - 1 + px;
        u16x8 v = (u16x8){0, 0, 0, 0, 0, 0, 0, 0};
        if ((unsigned)gy < 128u && (unsigned)gx < 128u)
            v = *(const u16x8*)(src + ((size_t)gy * 128 + gx) * CH + s * 8);
        *(u16x8*)&st[(row * 34 + px) * 256 + ((s ^ (px & 7)) * 8)] = v;
    }
    __syncthreads();

    floatx4 acc[2];
    acc[0] = (floatx4){0.f, 0.f, 0.f, 0.f};
    acc[1] = (floatx4){0.f, 0.f, 0.f, 0.f};

    #pragma unroll
    for (int k0 = 0; k0 < 2; ++k0) {
        #pragma unroll
        for (int t = 0; t < 9; ++t) {
            const int row = t / 3, dxi = t % 3;
            const int srd = w * 8 + k0 * 4 + quad;
            #pragma unroll
            for (int j = 0; j < 2; ++j) {
                int px = j * 16 + l15 + dxi;        // 0..33
                short8 a = *(const short8*)&st[(row * 34 + px) * 256
                                               + ((srd ^ (px & 7)) * 8)];
                acc[j] = __builtin_amdgcn_mfma_f32_16x16x32_bf16(
                    a, bw[t][k0], acc[j], 0, 0, 0);
            }
        }
    }

    __syncthreads();
    float* red = (float*)st;            // [4 waves][32 px][16 oc]
    #pragma unroll
    for (int j = 0; j < 2; ++j)
        #pragma unroll
        for (int r = 0; r < 4; ++r)
            red[(w * 32 + j * 16 + quad * 4 + r) * 16 + l15] = acc[j][r];
    __syncthreads();

    const int oc = tid >> 5, px = tid & 31;   // 8 oc x 32 px = 256 threads
    float s0 = red[px * 16 + oc]        + red[(32 + px) * 16 + oc]
             + red[(64 + px) * 16 + oc] + red[(96 + px) * 16 + oc];
    offs[((size_t)b * 8 + oc) * HW2 + (size_t)y * 128 + xq * 32 + px] = s0;
}

// ---------------------------------------------------------------------------
// K4: deformable 4-point border-clamped bilinear sample of procT, averaged.
// v3: occupancy-optimized.  LDS 19.9 KB (4-px transpose tiles stride-264 =
// 2-way-free banks; packed per-px params: idx|flags int + (fx,fy) float2,
// weights recomputed in-loop) -> 8 blocks/CU (32 waves, whole grid resident).
// __launch_bounds__(256,8) caps VGPR at 64.
// ---------------------------------------------------------------------------
__global__ __launch_bounds__(256, 8) void k4_sample(
    const float* __restrict__ offs, const float* __restrict__ b2v,
    const float* __restrict__ procT, float* __restrict__ out)
{
    const int blk = blockIdx.x;
    const int b  = blk & 7;
    const int r  = blk >> 3;       // 0..255
    const int y  = r >> 1;
    const int xh = r & 1;          // 64-px half row
    const int tid = threadIdx.x;
    const int lane = tid & 63, w = tid >> 6;

    __shared__ int    sp_i[4][64];     // [p][px]: idx | dxflag<<20 | dyflag<<21
    __shared__ float2 sp_f[4][64];     // [p][px]: fx, fy
    __shared__ float  tile[4][4 * 264];

    if (tid < 64) {
        int x = xh * 64 + tid;
        float gxb = (2.0f * x) / 127.0f - 1.0f;
        float gyb = (2.0f * y) / 127.0f - 1.0f;
        const float* ob = offs + (size_t)b * 8 * HW2 + y * 128 + x;
        #pragma unroll
        for (int p = 0; p < 4; ++p) {
            float ox = ob[(2 * p) * HW2] + b2v[2 * p];
            float oy = ob[(2 * p + 1) * HW2] + b2v[2 * p + 1];
            float gx = gxb + ox * (2.0f / 128.0f);
            float gy = gyb + oy * (2.0f / 128.0f);
            float gxp = fminf(fmaxf((gx + 1.0f) * 32.0f - 0.5f, 0.0f), 63.0f);
            float gyp = fminf(fmaxf((gy + 1.0f) * 32.0f - 0.5f, 0.0f), 63.0f);
            float x0f = floorf(gxp), y0f = floorf(gyp);
            int x0 = (int)x0f, y0 = (int)y0f;
            int idx = (y0 * 64 + x0) * 256;          // < 2^20
            int fl  = ((x0 < 63) ? (1 << 20) : 0) | ((y0 < 63) ? (1 << 21) : 0);
            sp_i[p][tid] = idx | fl;
            sp_f[p][tid] = make_float2(gxp - x0f, gyp - y0f);
        }
    }
    __syncthreads();

    const float* P = procT + (size_t)b * HW0 * CH + lane * 4;
    float* tw = &tile[w][0];
    float* outb = out + (size_t)b * CH * HW2 + (size_t)y * 128 + xh * 64 + w * 16;

    for (int c4 = 0; c4 < 4; ++c4) {
        #pragma unroll
        for (int i = 0; i < 4; ++i) {
            int lpx = w * 16 + c4 * 4 + i;     // local px, uniform per wave
            float4 a = make_float4(0.f, 0.f, 0.f, 0.f);
            #pragma unroll
            for (int p = 0; p < 4; ++p) {
                int si = sp_i[p][lpx];
                float2 f = sp_f[p][lpx];
                int idx = si & 0xFFFFF;
                int dxo = (si & (1 << 20)) ? 256 : 0;
                int dyo = (si & (1 << 21)) ? 16384 : 0;
                float fx = f.x, fy = f.y;
                float ex = 1.0f - fx, ey = 1.0f - fy;
                float w00 = ex * ey, w01 = fx * ey, w10 = ex * fy, w11 = fx * fy;
                const float* qp = P + idx;
                float4 v00 = *(const float4*)(qp);
                float4 v01 = *(const float4*)(qp + dxo);
                float4 v10 = *(const float4*)(qp + dyo);
                float4 v11 = *(const float4*)(qp + dyo + dxo);
                a.x += w00 * v00.x + w01 * v01.x + w10 * v10.x + w11 * v11.x;
                a.y += w00 * v00.y + w01 * v01.y + w10 * v10.y + w11 * v11.y;
                a.z += w00 * v00.z + w01 * v01.z + w10 * v10.z + w11 * v11.z;
                a.w += w00 * v00.w + w01 * v01.w + w10 * v10.w + w11 * v11.w;
            }
            a.x *= 0.25f; a.y *= 0.25f; a.z *= 0.25f; a.w *= 0.25f;
            *(float4*)&tw[i * 264 + lane * 4] = a;
        }
        __syncthreads();
        // transposed write: 4 px x 256 ch; read banks 2-way (stride 264)
        #pragma unroll
        for (int g = 0; g < 16; ++g) {
            int c   = g * 16 + (lane >> 2);
            int pxl = lane & 3;
            outb[(size_t)c * HW2 + c4 * 4 + pxl] = tw[pxl * 264 + c];
        }
        __syncthreads();
    }
}

// ---------------------------------------------------------------------------
extern "C" void kernel_launch(void* const* d_in, const int* in_sizes, int n_in,
                              void* d_out, int out_size, void* d_ws, size_t ws_size,
                              hipStream_t stream) {
    const float* high = (const float*)d_in[0];
    const float* low  = (const float*)d_in[1];
    const float* W1   = (const float*)d_in[2];
    const float* b1   = (const float*)d_in[3];
    const float* W2v  = (const float*)d_in[4];
    const float* b2v  = (const float*)d_in[5];
    const float* Wf   = (const float*)d_in[6];
    const float* bfv  = (const float*)d_in[7];
    float* out = (float*)d_out;
    float* ws  = (float*)d_ws;

    // ws layout (floats):
    float* T     = ws;                       // 8*256*4096  = 8388608
    float* procT = ws + 8388608;             // 8388608  ([B][4096][256])
    float* offs  = ws + 16777216;            // 1048576
    unsigned short* highT = (unsigned short*)(ws + 17825792);  // 8388608 shorts
    unsigned short* A1 = highT + 8388608;   // 131072 shorts
    unsigned short* A2 = A1 + 131072;       // 65536 shorts  (total ~88.5 MB)

    // W3p reuses highT's storage — written only AFTER k1 (highT dead by then).
    unsigned short* W3p = highT;            // 36864 shorts

    // d_out (33554432 floats = 134 MB) doubles as scratch (upper half):
    unsigned short* off_featT = ((unsigned short*)out) + 33554432;

    // transpose+convert high to bf16 [b][m][256]  (low fused into k2)
    ktrans<<<dim3(32, 8, NB), 256, 0, stream>>>(high, highT, HW0);
    kwconv<<<dim3(512), 256, 0, stream>>>(W1, Wf, A1, A2);

    // T = W1a@high (row-major), procT = (Wf@high + bf) transposed
    k1_mfma<<<dim3(1024), 256, 0, stream>>>(highT, A1, bfv, T, procT);
    // pack conv3x3 weights (over dead highT region)
    kwpack<<<dim3(144), 256, 0, stream>>>(W2v, W3p);
    // off_featT = relu(W1b@low + up2x(T) + b1)  (f32 low staged in-kernel)
    k2_mfma<<<dim3(2048), 256, 0, stream>>>(low, A2, b1, T, off_featT);
    // offs = conv3x3(off_featT, W2)  (MFMA, LDS-staged, XCD-affine)
    k3_mfma<<<dim3(4096), 256, 0, stream>>>(off_featT, W3p, offs);
    // out = mean over 4 deformable bilinear samples of procT
    k4_sample<<<dim3(2048), 256, 0, stream>>>(offs, b2v, procT, out);
}